// Round 3
// baseline (1803.012 us; speedup 1.0000x reference)
//
#include <hip/hip_runtime.h>
#include <math.h>

#define TOKENS 16384
#define HIDDEN 7168
#define NEXP   256
#define TOPK   8
#define KS     64
#define NSTEP  (HIDDEN / KS)      // 112
#define SMEM_MAIN (1024 + 16384 + 64 * 257 * 4)   // bias + A-stage + score plane = 83200

typedef __attribute__((ext_vector_type(4))) int i32x4;

// B limb layout: byte addr = ((s*4 + p)*256 + n)*64 + k'  (slice s, limb p, expert n, k')
// total 112*4*256*64 = 7,340,032 B in d_ws

// ---------------------------------------------------------------------------
// prep: W[256][7168] fp32 -> 4 signed-digit int8 limb planes of round(w * 2^31)
// ---------------------------------------------------------------------------
__global__ __launch_bounds__(256) void prep_b(const float* __restrict__ w, char* __restrict__ bl)
{
    const int g = blockIdx.x * 256 + threadIdx.x;   // 448*256 threads, 16 elems each
    const int e = g * 16;
    const int n = e / HIDDEN;
    const int k = e % HIDDEN;
    const int s = k >> 6;
    const int kc = (k >> 4) & 3;
    unsigned pk[4][4];   // [limb][4-elem group]
#pragma unroll
    for (int grp = 0; grp < 4; ++grp) {
        const float4 v = *(const float4*)(w + e + grp * 4);
        const float xs[4] = {v.x, v.y, v.z, v.w};
        unsigned a0 = 0, a1 = 0, a2 = 0, a3 = 0;
#pragma unroll
        for (int c = 0; c < 4; ++c) {
            const int X  = (int)rintf(xs[c] * 2147483648.0f);  // w * 2^31 (|X| < 2.5e8)
            const int X1 = (X  + 128) >> 8;                    // signed base-256 digits
            const int X2 = (X1 + 128) >> 8;
            const int X3 = (X2 + 128) >> 8;
            a0 |= (unsigned)((X  - (X1 << 8)) & 255) << (8 * c);
            a1 |= (unsigned)((X1 - (X2 << 8)) & 255) << (8 * c);
            a2 |= (unsigned)((X2 - (X3 << 8)) & 255) << (8 * c);
            a3 |= (unsigned)( X3              & 255) << (8 * c);
        }
        pk[0][grp] = a0; pk[1][grp] = a1; pk[2][grp] = a2; pk[3][grp] = a3;
    }
#pragma unroll
    for (int p = 0; p < 4; ++p) {
        i32x4 d = {(int)pk[p][0], (int)pk[p][1], (int)pk[p][2], (int)pk[p][3]};
        *(i32x4*)(bl + (((size_t)(s * 4 + p) * NEXP + n) * 64 + kc * 16)) = d;
    }
}

// ---------------------------------------------------------------------------
// main: exact multi-limb i8 MFMA GEMM (64 tok x 256 experts / WG)
//       + fp32-faithful routing epilogue (mirrors np f32 score pipeline).
// grid 256 (1 block/CU), block 256 (wave w owns experts w*64..+63)
// ---------------------------------------------------------------------------
__global__ __launch_bounds__(256, 1) void router_main(
        const float* __restrict__ Xg,
        const float* __restrict__ bias,
        const char* __restrict__ BL,
        float* __restrict__ outI,
        float* __restrict__ outW)
{
    extern __shared__ char smem[];
    float* biasL = (float*)smem;                      // [256] f32
    char*  stage = smem + 1024;                       // [4][64][64] i8 = 16384
    float* plane = (float*)(smem + 1024 + 16384);     // [64][257] f32 scores

    const int tid  = threadIdx.x;
    const int b    = blockIdx.x;
    const int wave = tid >> 6;
    const int lane = tid & 63;
    const int l15  = lane & 15;
    const int q    = lane >> 4;

    biasL[tid] = bias[tid];

    const int arow = tid >> 2;      // token row 0..63
    const int akc  = tid & 3;       // 16-k chunk
    const float* aptr = Xg + (size_t)(b * 64 + arow) * HIDDEN + akc * 16;
    char* stw = stage + arow * 64 + akc * 16;

    i32x4 acc[5][4][4];
#pragma unroll
    for (int t = 0; t < 5; ++t)
#pragma unroll
        for (int i = 0; i < 4; ++i)
#pragma unroll
            for (int j = 0; j < 4; ++j)
                acc[t][i][j] = (i32x4){0, 0, 0, 0};

    float xs[16];
#pragma unroll
    for (int i = 0; i < 4; ++i) {
        const float4 v = *(const float4*)(aptr + i * 4);
        xs[i*4+0] = v.x; xs[i*4+1] = v.y; xs[i*4+2] = v.z; xs[i*4+3] = v.w;
    }

    for (int s = 0; s < NSTEP; ++s) {
        __syncthreads();   // previous step's LDS readers are done

        // hoist this step's 16 B fragment loads (L2); consumed after barrier
        i32x4 bf[4][4];
        const char* bs = BL + (size_t)s * 65536 + (size_t)(wave * 64 + l15) * 64 + q * 16;
#pragma unroll
        for (int j = 0; j < 4; ++j)
#pragma unroll
            for (int p = 0; p < 4; ++p)
                bf[j][p] = *(const i32x4*)(bs + p * 16384 + j * 1024);

        // convert this step's A (xs) to 4 limb planes, stage to LDS
        unsigned pk[4][4];
#pragma unroll
        for (int grp = 0; grp < 4; ++grp) {
            unsigned a0 = 0, a1 = 0, a2 = 0, a3 = 0;
#pragma unroll
            for (int c = 0; c < 4; ++c) {
                const int X  = (int)rintf(xs[grp*4+c] * 268435456.0f);  // x * 2^28
                const int X1 = (X  + 128) >> 8;
                const int X2 = (X1 + 128) >> 8;
                const int X3 = (X2 + 128) >> 8;
                a0 |= (unsigned)((X  - (X1 << 8)) & 255) << (8 * c);
                a1 |= (unsigned)((X1 - (X2 << 8)) & 255) << (8 * c);
                a2 |= (unsigned)((X2 - (X3 << 8)) & 255) << (8 * c);
                a3 |= (unsigned)( X3              & 255) << (8 * c);
            }
            pk[0][grp] = a0; pk[1][grp] = a1; pk[2][grp] = a2; pk[3][grp] = a3;
        }
#pragma unroll
        for (int p = 0; p < 4; ++p) {
            i32x4 d = {(int)pk[p][0], (int)pk[p][1], (int)pk[p][2], (int)pk[p][3]};
            *(i32x4*)(stw + p * 4096) = d;
        }
        __syncthreads();

        // HBM prefetch of next step's A (consumed next iteration)
        if (s + 1 < NSTEP) {
#pragma unroll
            for (int i = 0; i < 4; ++i) {
                const float4 v = *(const float4*)(aptr + (s + 1) * KS + i * 4);
                xs[i*4+0] = v.x; xs[i*4+1] = v.y; xs[i*4+2] = v.z; xs[i*4+3] = v.w;
            }
        }

        // MFMAs: 16 tiles x 13 planes (pa+pb >= 2), acc shared per total weight
#pragma unroll
        for (int i = 0; i < 4; ++i) {
            i32x4 af[4];
#pragma unroll
            for (int p = 0; p < 4; ++p)
                af[p] = *(const i32x4*)(stage + p * 4096 + (i * 16 + l15) * 64 + q * 16);
#pragma unroll
            for (int j = 0; j < 4; ++j)
#pragma unroll
                for (int pa = 0; pa < 4; ++pa)
#pragma unroll
                    for (int pb = 0; pb < 4; ++pb)
                        if (pa + pb >= 2)
                            acc[pa + pb - 2][i][j] = __builtin_amdgcn_mfma_i32_16x16x64_i8(
                                af[pa], bf[j][pb], acc[pa + pb - 2][i][j], 0, 0, 0);
        }
    }

    // ---- epilogue: exact combine (f64) -> f32 logit -> f32 sigmoid pipeline
    // C/D layout: col = lane&15 (n), row = q*4 + reg (m)
#pragma unroll
    for (int i = 0; i < 4; ++i)
#pragma unroll
        for (int j = 0; j < 4; ++j)
#pragma unroll
            for (int r = 0; r < 4; ++r) {
                const double S = ((((double)acc[4][i][j][r] * 256.0 + (double)acc[3][i][j][r]) * 256.0
                                  + (double)acc[2][i][j][r]) * 256.0 + (double)acc[1][i][j][r]) * 256.0
                                  + (double)acc[0][i][j][r];
                const float lg = (float)(S * 0x1p-43);            // f32 logit (RNE)
                const float e  = (float)exp(-(double)lg);         // correctly-rounded f32 exp
                const float sc = 1.0f / (1.0f + e);               // f32 ops, mirrors np
                plane[(i * 16 + q * 4 + r) * 257 + (wave * 64 + j * 16 + l15)] = sc;
            }
    __syncthreads();

    // ---- routing on f32 values, stable lower-index tie-breaks (wave 0)
    if (tid < 64) {
        const float* row = plane + tid * 257;
        float gs[8];
#pragma unroll
        for (int g = 0; g < 8; ++g) {                  // per-group top-2 sum (f32)
            float m1 = -1e30f, m2 = -1e30f;
            for (int k = 0; k < 32; ++k) {
                const float v = row[g * 32 + k] + biasL[g * 32 + k];
                if (v > m1) { m2 = m1; m1 = v; }
                else if (v > m2) { m2 = v; }
            }
            gs[g] = m1 + m2;                           // descending-order f32 add
        }
        unsigned gmask = 0;                            // top-4 groups, stable
#pragma unroll
        for (int rs = 0; rs < 4; ++rs) {
            float best = -1e30f; int bg = 0;
            for (int g = 0; g < 8; ++g)
                if (!((gmask >> g) & 1) && gs[g] > best) { best = gs[g]; bg = g; }
            gmask |= 1u << bg;
        }
        float tv[8]; int ti[8];                        // stable top-8, masked = 0.0f
#pragma unroll
        for (int j = 0; j < 8; ++j) { tv[j] = -1e30f; ti[j] = 0; }
        for (int e = 0; e < 256; ++e) {
            const float v = ((gmask >> (e >> 5)) & 1) ? (row[e] + biasL[e]) : 0.0f;
            if (v > tv[7]) {
                int p = 7;
                while (p > 0 && v > tv[p - 1]) { tv[p] = tv[p - 1]; ti[p] = ti[p - 1]; --p; }
                tv[p] = v; ti[p] = e;
            }
        }
        float sum = 0.f, wv[8];
#pragma unroll
        for (int j = 0; j < 8; ++j) { wv[j] = row[ti[j]]; sum += wv[j]; }  // raw f32 sigmoid
        const float denom = sum + 1e-20f;
        const size_t o = ((size_t)b * 64 + tid) * TOPK;
#pragma unroll
        for (int j = 0; j < 8; ++j) {
            outI[o + j] = (float)ti[j];
            outW[o + j] = wv[j] / denom * 2.5f;
        }
    }
}

// ---------------------------------------------------------------------------
extern "C" void kernel_launch(void* const* d_in, const int* in_sizes, int n_in,
                              void* d_out, int out_size, void* d_ws, size_t ws_size,
                              hipStream_t stream)
{
    const float* X    = (const float*)d_in[0];
    const float* W    = (const float*)d_in[1];
    const float* bias = (const float*)d_in[2];

    char* BL = (char*)d_ws;                            // 7,340,032 B limb planes
    float* outI = (float*)d_out;
    float* outW = outI + (size_t)TOKENS * TOPK;

    prep_b<<<448, 256, 0, stream>>>(W, BL);

    (void)hipFuncSetAttribute((const void*)router_main,
                              hipFuncAttributeMaxDynamicSharedMemorySize, SMEM_MAIN);
    router_main<<<TOKENS / 64, 256, SMEM_MAIN, stream>>>(X, bias, BL, outI, outW);
}